// Round 2
// baseline (901.607 us; speedup 1.0000x reference)
//
#include <hip/hip_runtime.h>

// SelectivePSI forward: bf16 MFMA GEMMs + chunked parallel scans.
// B=4, S=4096, D=1024, R=128. fp32 in/out, bf16 internals.
// Processed in TWO half-batches (B=2 each) to keep workspace ~158 MB.

#define D_ 1024
#define S_ 4096
#define BH 2                 // batches per half-pass
#define MH (BH*S_)           // 8192 tokens per half
#define CHUNK 64
#define NCH (S_/CHUNK)       // 64 chunks per sequence

typedef float f32x4 __attribute__((ext_vector_type(4)));
typedef __bf16 bf16x8 __attribute__((ext_vector_type(8)));
typedef short s16x8 __attribute__((ext_vector_type(8)));

typedef __attribute__((address_space(1))) void gvoid;
typedef __attribute__((address_space(3))) void lvoid;

__device__ __forceinline__ void g2l16(const void* g, void* l) {
  __builtin_amdgcn_global_load_lds((gvoid*)g, (lvoid*)l, 16, 0, 0);
}

__device__ __forceinline__ float bflo(unsigned int w){ union{unsigned int i; float f;} c; c.i = w<<16; return c.f; }
__device__ __forceinline__ float bfhi(unsigned int w){ union{unsigned int i; float f;} c; c.i = w & 0xFFFF0000u; return c.f; }
__device__ __forceinline__ unsigned short f2bf(float f){
  union{float f; unsigned int i;} c; c.f=f;
  unsigned int u = c.i + 0x7FFFu + ((c.i>>16)&1u);
  return (unsigned short)(u>>16);
}
__device__ __forceinline__ unsigned int pack2(float lo, float hi){
  return (unsigned int)f2bf(lo) | ((unsigned int)f2bf(hi)<<16);
}

__device__ __forceinline__ float sig_(float x){ return 1.f/(1.f+__expf(-x)); }
__device__ __forceinline__ float gelu_(float x){ return 0.5f*x*(1.f+erff(x*0.70710678118654752440f)); }
__device__ __forceinline__ float softplus_(float x){ return (x>0.f) ? x + log1pf(__expf(-x)) : log1pf(__expf(x)); }

// ---------------- GEMM: C[M,N] = A[M,K] @ Bt[N,K]^T, bf16 in, fused epilogue ---------
// 128x128 tile, BK=32, 256 threads (4 waves, 2x2 of 64x64), global_load_lds staging.
// mfma_f32_16x16x32_bf16: A lane holds A[l&15][8*(l>>4)+j]; D: row=4*(l>>4)+q, col=l&15.
template<int EPI>
__global__ __launch_bounds__(256)
void gemm128(const unsigned short* __restrict__ A, int lda,
             const unsigned short* __restrict__ Bt, int ldb,
             int K, int N,
             const float* __restrict__ bias,
             const float* __restrict__ extra,
             void* __restrict__ Cout)
{
  __shared__ unsigned short As[128*32];
  __shared__ unsigned short Bs[128*32];
  const int tid = threadIdx.x;
  const int m0 = blockIdx.x * 128;
  const int n0 = blockIdx.y * 128;
  const int lane = tid & 63;
  const int wv = tid >> 6;
  const int wr = wv >> 1, wc = wv & 1;
  const int fr = lane & 15, fg = lane >> 4;

  const int r0 = tid >> 2;              // staging chunk rows
  const int r1 = (tid + 256) >> 2;
  const int k8 = (tid & 3) * 8;

  f32x4 acc[4][4];
#pragma unroll
  for (int i=0;i<4;i++)
#pragma unroll
    for (int j=0;j<4;j++)
#pragma unroll
      for (int q=0;q<4;q++) acc[i][j][q] = 0.f;

  for (int k0 = 0; k0 < K; k0 += 32) {
    __syncthreads();   // previous iter's LDS readers done
    g2l16(A  + (size_t)(m0+r0)*lda + k0 + k8, As + (size_t)tid*8);
    g2l16(A  + (size_t)(m0+r1)*lda + k0 + k8, As + (size_t)(tid+256)*8);
    g2l16(Bt + (size_t)(n0+r0)*ldb + k0 + k8, Bs + (size_t)tid*8);
    g2l16(Bt + (size_t)(n0+r1)*ldb + k0 + k8, Bs + (size_t)(tid+256)*8);
    __syncthreads();   // compiler drains vmcnt before barrier

    s16x8 af[4], bfr[4];
#pragma unroll
    for (int mf=0; mf<4; mf++) af[mf]  = *(const s16x8*)&As[(wr*64 + mf*16 + fr)*32 + fg*8];
#pragma unroll
    for (int nf=0; nf<4; nf++) bfr[nf] = *(const s16x8*)&Bs[(wc*64 + nf*16 + fr)*32 + fg*8];
#pragma unroll
    for (int mf=0; mf<4; mf++)
#pragma unroll
      for (int nf=0; nf<4; nf++)
        acc[mf][nf] = __builtin_amdgcn_mfma_f32_16x16x32_bf16(
          __builtin_bit_cast(bf16x8, af[mf]), __builtin_bit_cast(bf16x8, bfr[nf]),
          acc[mf][nf], 0, 0, 0);
  }

#pragma unroll
  for (int mf=0; mf<4; mf++) {
#pragma unroll
    for (int nf=0; nf<4; nf++) {
      const int gn = n0 + wc*64 + nf*16 + fr;
      float bv = 0.f;
      if constexpr (EPI != 5) bv = bias[gn];
#pragma unroll
      for (int q=0; q<4; q++) {
        const int gm = m0 + wr*64 + mf*16 + fg*4 + q;
        const size_t idx = (size_t)gm * N + gn;
        const float z = acc[mf][nf][q] + bv;
        if constexpr      (EPI == 0) ((unsigned short*)Cout)[idx] = f2bf(sig_(z));            // gate
        else if constexpr (EPI == 1) ((unsigned short*)Cout)[idx] = f2bf(z + extra[gn]);      // omega (+omega_base)
        else if constexpr (EPI == 2) ((unsigned short*)Cout)[idx] = f2bf(gelu_(z));           // gelu
        else if constexpr (EPI == 3) ((unsigned short*)Cout)[idx] = f2bf(sig_(z)*5.f);        // magnitude
        else if constexpr (EPI == 4) ((unsigned short*)Cout)[idx] = f2bf(z);                  // linear+bias
        else if constexpr (EPI == 5) ((unsigned short*)Cout)[idx] = f2bf(z);                  // linear no bias
        else if constexpr (EPI == 6) ((unsigned short*)Cout)[idx] = f2bf(softplus_(z));       // dt
        else                         ((float*)Cout)[idx]          = z + extra[idx];           // out + x residual
      }
    }
  }
}

// ---------------- prep: fp32 -> bf16 convert / transpose-convert ----------------
__global__ __launch_bounds__(256)
void cvtx_k(const float* __restrict__ x, unsigned int* __restrict__ hb)
{
  const size_t i = (size_t)blockIdx.x*256 + threadIdx.x;
  const float4 v = *(const float4*)(x + i*4);
  hb[i*2]   = pack2(v.x, v.y);
  hb[i*2+1] = pack2(v.z, v.w);
}

__global__ __launch_bounds__(256)
void tconv_k(const float* __restrict__ W, unsigned short* __restrict__ Wt, int K, int N)
{
  __shared__ float tile[32][33];
  const int kb = blockIdx.x*32, nb = blockIdx.y*32;
  const int tx = threadIdx.x & 31, ty = threadIdx.x >> 5;   // 32x8
#pragma unroll
  for (int i=0;i<32;i+=8) tile[ty+i][tx] = W[(size_t)(kb+ty+i)*N + (nb+tx)];
  __syncthreads();
#pragma unroll
  for (int i=0;i<32;i+=8) Wt[(size_t)(nb+ty+i)*K + (kb+tx)] = f2bf(tile[tx][ty+i]);
}

// ---------------- scans: thread = (b, chunk, d-pair), loops CHUNK steps ----------------
// indices are within one half-pass: bc in [0, BH*NCH)
__global__ __launch_bounds__(256)
void scan1_k(unsigned int* __restrict__ zgate, unsigned int* __restrict__ zmag,
             unsigned int* __restrict__ zomega, const unsigned int* __restrict__ zdt,
             const unsigned int* __restrict__ hb,
             float* __restrict__ sumPhi, float* __restrict__ sumGm)
{
  const int flat = blockIdx.x*256 + threadIdx.x;   // BH*NCH*(D/2) = 65536
  const int dh = flat & 511;
  const int bc = flat >> 9;                        // [0, 128)
  size_t i = (size_t)bc*CHUNK*(D_/2) + dh;
  float sp0=0,sp1=0,sg0=0,sg1=0;
  for (int s=0;s<CHUNK;s++,i+=D_/2) {
    const unsigned ga=zgate[i], mg=zmag[i], om=zomega[i], dt=zdt[i], hh=hb[i];
    const float ga0=bflo(ga), ga1=bfhi(ga), mg0=bflo(mg), mg1=bfhi(mg);
    const float od0 = bflo(om)*bflo(dt)*0.01f, od1 = bfhi(om)*bfhi(dt)*0.01f;
    const unsigned odp = pack2(od0, od1);
    zomega[i] = odp;
    sp0 += bflo(odp); sp1 += bfhi(odp);            // sum the rounded values (consistency)
    const float g0 = ga0*mg0, g1 = ga1*mg1;
    const unsigned gmp = pack2(g0, g1);
    zmag[i] = gmp;
    sg0 += bflo(gmp); sg1 += bfhi(gmp);
    zgate[i] = pack2(g0*bflo(hh), g1*bfhi(hh));    // content = gate*h*mag
  }
  const int sidx = bc*D_ + dh*2;
  sumPhi[sidx]=sp0; sumPhi[sidx+1]=sp1;
  sumGm[sidx]=sg0;  sumGm[sidx+1]=sg1;
}

// exclusive scan of chunk sums over NCH, per (b,d) chain; two arrays at once
__global__ __launch_bounds__(256)
void scan2_k(float* __restrict__ a, float* __restrict__ b)
{
  const int ch = blockIdx.x*256 + threadIdx.x;     // BH*D = 2048
  const int bb = ch >> 10, d = ch & 1023;
  float r0=0.f, r1=0.f;
  for (int c=0;c<NCH;c++) {
    const size_t i = (size_t)(bb*NCH + c)*D_ + d;
    const float t=a[i]; a[i]=r0; r0+=t;
    const float u=b[i]; b[i]=r1; r1+=u;
  }
}

// S3: chunk partial sums of content*cos(phi), content*sin(phi)
__global__ __launch_bounds__(256)
void scan3_k(const unsigned int* __restrict__ omdt, const unsigned int* __restrict__ content,
             const unsigned int* __restrict__ phinit, const float* __restrict__ phiOff,
             float* __restrict__ sumRe, float* __restrict__ sumIm)
{
  const int flat = blockIdx.x*256 + threadIdx.x;
  const int dh = flat & 511;
  const int bc = flat >> 9;
  size_t i = (size_t)bc*CHUNK*(D_/2) + dh;
  const int sidx = bc*D_ + dh*2;
  float p0 = phiOff[sidx], p1 = phiOff[sidx+1];
  float re0=0,re1=0,im0=0,im1=0;
  for (int s=0;s<CHUNK;s++,i+=D_/2) {
    const unsigned od = omdt[i], ct = content[i], pi = phinit[i];
    p0 += bflo(od); p1 += bfhi(od);
    const float phi0 = bflo(pi)+p0, phi1 = bfhi(pi)+p1;
    float s0,c0,s1,c1;
    __sincosf(phi0,&s0,&c0);
    __sincosf(phi1,&s1,&c1);
    const float ct0=bflo(ct), ct1=bfhi(ct);
    re0 += ct0*c0; im0 += ct0*s0;
    re1 += ct1*c1; im1 += ct1*s1;
  }
  sumRe[sidx]=re0; sumRe[sidx+1]=re1;
  sumIm[sidx]=im0; sumIm[sidx+1]=im1;
}

// S5: final sweep -> ctx = [retrieved_real | retrieved_imag] (bf16, [MH][2048])
__global__ __launch_bounds__(256)
void scan5_k(const unsigned int* __restrict__ omdt, const unsigned int* __restrict__ content,
             const unsigned int* __restrict__ phinit, const unsigned int* __restrict__ gm,
             const unsigned int* __restrict__ qoff,
             const float* __restrict__ phiOff, const float* __restrict__ gmOff,
             const float* __restrict__ reOff, const float* __restrict__ imOff,
             unsigned int* __restrict__ ctx)
{
  const int flat = blockIdx.x*256 + threadIdx.x;
  const int dh = flat & 511;
  const int bc = flat >> 9;
  size_t i = (size_t)bc*CHUNK*(D_/2) + dh;
  const int sidx = bc*D_ + dh*2;
  float p0 = phiOff[sidx], p1 = phiOff[sidx+1];
  float ag0 = gmOff[sidx], ag1 = gmOff[sidx+1];
  float re0 = reOff[sidx], re1 = reOff[sidx+1];
  float im0 = imOff[sidx], im1 = imOff[sidx+1];
  const int mtok0 = bc*CHUNK;
  for (int s=0;s<CHUNK;s++,i+=D_/2) {
    const unsigned od = omdt[i], ct = content[i], pi = phinit[i], gq = gm[i], qo = qoff[i];
    p0 += bflo(od); p1 += bfhi(od);
    const float phi0 = bflo(pi)+p0, phi1 = bfhi(pi)+p1;
    float sn0,cs0,sn1,cs1;
    __sincosf(phi0,&sn0,&cs0);
    __sincosf(phi1,&sn1,&cs1);
    const float ct0=bflo(ct), ct1=bfhi(ct);
    re0 += ct0*cs0; im0 += ct0*sn0;
    re1 += ct1*cs1; im1 += ct1*sn1;
    ag0 += bflo(gq); ag1 += bfhi(gq);
    const float inv0 = rsqrtf(ag0 + 1e-8f), inv1 = rsqrtf(ag1 + 1e-8f);
    const float mr0 = re0*inv0, mi0 = im0*inv0;
    const float mr1 = re1*inv1, mi1 = im1*inv1;
    const float pq0 = phi0 + bflo(qo), pq1 = phi1 + bfhi(qo);
    float sq0,cq0,sq1,cq1;
    __sincosf(pq0,&sq0,&cq0);
    __sincosf(pq1,&sq1,&cq1);
    const size_t cb = (size_t)(mtok0+s)*D_ + dh;           // u32 row = 1024
    ctx[cb]        = pack2(mr0*cq0 + mi0*sq0, mr1*cq1 + mi1*sq1);
    ctx[cb + D_/2] = pack2(mi0*cq0 - mr0*sq0, mi1*cq1 - mr1*sq1);
  }
}

// LayerNorm over 2048, in place on bf16 ctx; one block per token
__global__ __launch_bounds__(256)
void ln_k(unsigned int* __restrict__ ctx, const float* __restrict__ gam, const float* __restrict__ bet)
{
  const int m = blockIdx.x, tid = threadIdx.x;
  const size_t base = (size_t)m*1024 + tid*4;
  const uint4 t = *(const uint4*)(ctx + base);
  float v[8] = { bflo(t.x), bfhi(t.x), bflo(t.y), bfhi(t.y),
                 bflo(t.z), bfhi(t.z), bflo(t.w), bfhi(t.w) };
  float s=0.f, ss=0.f;
#pragma unroll
  for (int j=0;j<8;j++){ s+=v[j]; ss+=v[j]*v[j]; }
  for (int o=32;o;o>>=1){ s += __shfl_xor(s,o); ss += __shfl_xor(ss,o); }
  __shared__ float red[8];
  const int wv = tid>>6, lane = tid&63;
  if (lane==0){ red[wv]=s; red[4+wv]=ss; }
  __syncthreads();
  s  = red[0]+red[1]+red[2]+red[3];
  ss = red[4]+red[5]+red[6]+red[7];
  const float mu = s*(1.f/2048.f);
  const float rstd = rsqrtf(ss*(1.f/2048.f) - mu*mu + 1e-5f);
  const int col = tid*8;
  float o[8];
#pragma unroll
  for (int j=0;j<8;j++) o[j] = (v[j]-mu)*rstd*gam[col+j] + bet[col+j];
  uint4 w;
  w.x = pack2(o[0],o[1]); w.y = pack2(o[2],o[3]);
  w.z = pack2(o[4],o[5]); w.w = pack2(o[6],o[7]);
  *(uint4*)(ctx + base) = w;
}

extern "C" void kernel_launch(void* const* d_in, const int* in_sizes, int n_in,
                              void* d_out, int out_size, void* d_ws, size_t ws_size,
                              hipStream_t stream)
{
  const float* x     = (const float*)d_in[0];
  const float* Wdd   = (const float*)d_in[1];
  const float* Wdu   = (const float*)d_in[2];
  const float* bdu   = (const float*)d_in[3];
  const float* Wg    = (const float*)d_in[4];
  const float* bg    = (const float*)d_in[5];
  const float* Wp1   = (const float*)d_in[6];
  const float* bp1   = (const float*)d_in[7];
  const float* Wp2   = (const float*)d_in[8];
  const float* bp2   = (const float*)d_in[9];
  const float* obase = (const float*)d_in[10];
  const float* Wo    = (const float*)d_in[11];
  const float* bo    = (const float*)d_in[12];
  const float* Wm    = (const float*)d_in[13];
  const float* bm    = (const float*)d_in[14];
  const float* Wq    = (const float*)d_in[15];
  const float* bq    = (const float*)d_in[16];
  const float* lng   = (const float*)d_in[17];
  const float* lnb   = (const float*)d_in[18];
  const float* Wo1   = (const float*)d_in[19];
  const float* bo1   = (const float*)d_in[20];
  const float* Wo2   = (const float*)d_in[21];
  const float* bo2   = (const float*)d_in[22];

  char* basep = (char*)d_ws;
  size_t off = 0;
  auto alloc = [&](size_t n) { char* q = basep + off; off = (off + n + 255) & ~(size_t)255; return q; };

  const size_t HZ = (size_t)MH*D_*2;    // 16,777,216 B (256-aligned)
  unsigned short* hb    = (unsigned short*)alloc(HZ);   // | ctx (33.5MB) aliases hb+zdt
  unsigned short* zdt   = (unsigned short*)alloc(HZ);   // | (both dead before scan5)
  unsigned short* ctx   = hb;
  unsigned short* zgate = (unsigned short*)alloc(HZ);   // -> content after S1
  unsigned short* zomega= (unsigned short*)alloc(HZ);   // -> omega*dt*0.01 after S1
  unsigned short* zmag  = (unsigned short*)alloc(HZ);   // -> gate*mag after S1
  unsigned short* zqoff = (unsigned short*)alloc(HZ);
  unsigned short* zpin  = (unsigned short*)alloc(HZ);   // phi_init
  unsigned short* zphi1 = (unsigned short*)alloc(HZ);   // dead after p2 GEMM; reused as a3
  unsigned short* a3    = zphi1;
  unsigned short* t1    = (unsigned short*)alloc((size_t)MH*128*2);
  unsigned short* wt_g  = (unsigned short*)alloc(1024*1024*2);
  unsigned short* wt_o  = (unsigned short*)alloc(1024*1024*2);
  unsigned short* wt_p1 = (unsigned short*)alloc(1024*1024*2);
  unsigned short* wt_m  = (unsigned short*)alloc(1024*1024*2);
  unsigned short* wt_q  = (unsigned short*)alloc(1024*1024*2);
  unsigned short* wt_p2 = (unsigned short*)alloc(1024*1024*2);
  unsigned short* wt_o2 = (unsigned short*)alloc(1024*1024*2);
  unsigned short* wt_dd = (unsigned short*)alloc(128*1024*2);
  unsigned short* wt_du = (unsigned short*)alloc(1024*128*2);
  unsigned short* wt_o1 = (unsigned short*)alloc((size_t)1024*2048*2);
  float* sumPhi = (float*)alloc((size_t)BH*NCH*D_*4);
  float* sumGm  = (float*)alloc((size_t)BH*NCH*D_*4);
  float* sumRe  = (float*)alloc((size_t)BH*NCH*D_*4);
  float* sumIm  = (float*)alloc((size_t)BH*NCH*D_*4);
  // total ~158 MB

  const dim3 blk(256);

  // one-time weight transposes (fp32 -> bf16 [N][K])
  tconv_k<<<dim3(32,32), blk, 0, stream>>>(Wg,  wt_g,  1024,1024);
  tconv_k<<<dim3(32,32), blk, 0, stream>>>(Wo,  wt_o,  1024,1024);
  tconv_k<<<dim3(32,32), blk, 0, stream>>>(Wp1, wt_p1, 1024,1024);
  tconv_k<<<dim3(32,32), blk, 0, stream>>>(Wm,  wt_m,  1024,1024);
  tconv_k<<<dim3(32,32), blk, 0, stream>>>(Wq,  wt_q,  1024,1024);
  tconv_k<<<dim3(32,32), blk, 0, stream>>>(Wp2, wt_p2, 1024,1024);
  tconv_k<<<dim3(32,32), blk, 0, stream>>>(Wo2, wt_o2, 1024,1024);
  tconv_k<<<dim3(32,4),  blk, 0, stream>>>(Wdd, wt_dd, 1024,128);
  tconv_k<<<dim3(4,32),  blk, 0, stream>>>(Wdu, wt_du, 128,1024);
  tconv_k<<<dim3(64,32), blk, 0, stream>>>(Wo1, wt_o1, 2048,1024);

  for (int h = 0; h < 2; h++) {
    const float* xh  = x + (size_t)h*MH*D_;
    float* outh      = (float*)d_out + (size_t)h*MH*D_;

    cvtx_k<<<MH*D_/1024, blk, 0, stream>>>(xh, (unsigned int*)hb);

    const dim3 g8(MH/128, 8), g1(MH/128, 1);
    // phi path first so zphi1 dies early
    gemm128<2><<<g8, blk, 0, stream>>>(hb,1024,    wt_p1,1024, 1024,1024, bp1, nullptr, zphi1);
    gemm128<4><<<g8, blk, 0, stream>>>(zphi1,1024, wt_p2,1024, 1024,1024, bp2, nullptr, zpin);
    // remaining projections from h
    gemm128<0><<<g8, blk, 0, stream>>>(hb,1024,    wt_g,1024,  1024,1024, bg,  nullptr, zgate);
    gemm128<1><<<g8, blk, 0, stream>>>(hb,1024,    wt_o,1024,  1024,1024, bo,  obase,   zomega);
    gemm128<3><<<g8, blk, 0, stream>>>(hb,1024,    wt_m,1024,  1024,1024, bm,  nullptr, zmag);
    gemm128<4><<<g8, blk, 0, stream>>>(hb,1024,    wt_q,1024,  1024,1024, bq,  nullptr, zqoff);
    gemm128<5><<<g1, blk, 0, stream>>>(hb,1024,    wt_dd,1024, 1024,128,  nullptr,nullptr, t1);
    gemm128<6><<<g8, blk, 0, stream>>>(t1,128,     wt_du,128,  128,1024,  bdu, nullptr, zdt);

    // scans (256 blocks = BH*NCH*(D/2)/256)
    scan1_k<<<256, blk, 0, stream>>>((unsigned int*)zgate,(unsigned int*)zmag,(unsigned int*)zomega,
                                     (const unsigned int*)zdt,(const unsigned int*)hb, sumPhi, sumGm);
    scan2_k<<<8, blk, 0, stream>>>(sumPhi, sumGm);
    scan3_k<<<256, blk, 0, stream>>>((const unsigned int*)zomega,(const unsigned int*)zgate,
                                     (const unsigned int*)zpin, sumPhi, sumRe, sumIm);
    scan2_k<<<8, blk, 0, stream>>>(sumRe, sumIm);
    scan5_k<<<256, blk, 0, stream>>>((const unsigned int*)zomega,(const unsigned int*)zgate,
                                     (const unsigned int*)zpin,(const unsigned int*)zmag,
                                     (const unsigned int*)zqoff,
                                     sumPhi, sumGm, sumRe, sumIm, (unsigned int*)ctx);

    // layernorm + output MLP + residual
    ln_k<<<MH, blk, 0, stream>>>((unsigned int*)ctx, lng, lnb);
    gemm128<2><<<g8, blk, 0, stream>>>(ctx,2048, wt_o1,2048, 2048,1024, bo1, nullptr, a3);
    gemm128<7><<<g8, blk, 0, stream>>>(a3,1024,  wt_o2,1024, 1024,1024, bo2, xh, (float*)outh);
  }
}